// Round 12
// baseline (155.737 us; speedup 1.0000x reference)
//
#include <hip/hip_runtime.h>
#include <hip/hip_bf16.h>
#include <math.h>

#define N_NODES 8192
#define KNBR    32
#define PDIM    128
#define BINS    64
#define REL_CLIP 32
#define REL_DIM  66
#define RSTR    136   // LDS row stride in ushorts (272B): 4-bank row step, conflict-free, linear chunks

typedef unsigned short ushort_t;
typedef short v8s  __attribute__((ext_vector_type(8)));
typedef float v4f  __attribute__((ext_vector_type(4)));

__device__ __forceinline__ ushort_t f2bf(float f) {
    union { __hip_bfloat16 b; ushort_t u; } cv;
    cv.b = __float2bfloat16(f);
    return cv.u;
}
__device__ __forceinline__ unsigned int pk2bf(float lo, float hiv) {
    union { __hip_bfloat162 h2; unsigned int u; } cv;
    cv.h2 = __float22bfloat162_rn(make_float2(lo, hiv));
    return cv.u;
}
// gelu ~= x * sigmoid(1.702 x); exp(-1.702x) = exp2(-2.4554045x)
__device__ __forceinline__ float gelu_sig(float x) {
    float e = exp2f(-2.4554045f * x);
    return x / (1.f + e);
}

// ---------------- prep: bf16 weights; LN folded into W1/b1 ----------------
__global__ __launch_bounds__(256) void prep_kernel(
    const float* __restrict__ W_dist, const float* __restrict__ W_dir,
    const float* __restrict__ W_rot, const float* __restrict__ W_pvec,
    const float* __restrict__ W_relpos,
    const float* __restrict__ W1, const float* __restrict__ W2,
    const float* __restrict__ W_loc_i, const float* __restrict__ W_loc_j,
    const float* __restrict__ ln_scale, const float* __restrict__ ln_bias,
    const float* __restrict__ b1,
    ushort_t* __restrict__ Wcomb, ushort_t* __restrict__ W1Ts,
    ushort_t* __restrict__ W2T, ushort_t* __restrict__ W_locT,
    float* __restrict__ b1p)
{
    int idx = blockIdx.x * 256 + threadIdx.x;
    if (idx < 16384) {
        int col = idx >> 7, k = idx & 127;
        float v = 0.f;
        if (k < 16)       v = W_dist[k * PDIM + col];
        else if (k < 19)  v = W_dir[(k - 16) * PDIM + col];
        else if (k < 28)  v = W_rot[(k - 19) * PDIM + col];
        else if (k < 43)  v = W_pvec[(k - 28) * PDIM + col];
        else if (k < 109) v = W_relpos[(size_t)(k - 43) * PDIM + col];
        Wcomb[idx] = f2bf(v);
    } else if (idx < 49152) {
        int o = idx - 16384;
        int col = o >> 7, k = o & 127;
        W1Ts[o] = f2bf(W1[(size_t)k * 256 + col] * ln_scale[k]);
    } else if (idx < 65536) {
        int o = idx - 49152;
        int col = o >> 8, k = o & 255;
        W2T[o] = f2bf(W2[(size_t)k * BINS + col]);
    } else if (idx < 131072) {
        int o = idx - 65536;
        int oc = o >> 8, k = o & 255;
        float v = (oc < 128) ? W_loc_i[(size_t)k * 128 + oc]
                             : W_loc_j[(size_t)k * 128 + (oc - 128)];
        W_locT[o] = f2bf(v);
    } else if (idx < 131328) {
        int c = idx - 131072;
        float s = b1[c];
        for (int k = 0; k < 128; ++k) s += ln_bias[k] * W1[(size_t)k * 256 + c];
        b1p[c] = s;
    }
}

// ---------------- locframe: frames + MFMA local projections ----------------
__global__ __launch_bounds__(256) void locframe_kernel(
    const float* __restrict__ local, const float* __restrict__ pos,
    const ushort_t* __restrict__ W_locT,
    float* __restrict__ R_ws, float* __restrict__ loci_ws, float* __restrict__ locj_ws)
{
    __shared__ __align__(16) ushort_t LB[32 * 264];
    const int tid = threadIdx.x;
    const int base = blockIdx.x * 32;
    const int wid = tid >> 6, lane = tid & 63, c15 = lane & 15, hi = lane >> 4;

    if (tid < 32) {  // frames
        const int n = base + tid;
        const float* pp = pos + (size_t)n * 15;
        float nx = pp[0], ny = pp[1], nz = pp[2];
        float cax = pp[3], cay = pp[4], caz = pp[5];
        float cx = pp[6], cy = pp[7], cz = pp[8];
        float e1x = cx - cax, e1y = cy - cay, e1z = cz - caz;
        float n1 = sqrtf(e1x*e1x + e1y*e1y + e1z*e1z) + 1e-8f;
        e1x /= n1; e1y /= n1; e1z /= n1;
        float v2x = nx - cax, v2y = ny - cay, v2z = nz - caz;
        float dp = v2x*e1x + v2y*e1y + v2z*e1z;
        float wx = v2x - dp*e1x, wy = v2y - dp*e1y, wz = v2z - dp*e1z;
        float n2 = sqrtf(wx*wx + wy*wy + wz*wz) + 1e-8f;
        float e2x = wx/n2, e2y = wy/n2, e2z = wz/n2;
        float4 f0, f1, f2;
        f0.x = e1x; f0.y = e1y; f0.z = e1z; f0.w = e2x;
        f1.x = e2y; f1.y = e2z;
        f1.z = e1y*e2z - e1z*e2y;
        f1.w = e1z*e2x - e1x*e2z;
        f2.x = e1x*e2y - e1y*e2x;
        f2.y = 0.f; f2.z = 0.f; f2.w = 0.f;
        float* R = R_ws + (size_t)n * 12;
        *(float4*)&R[0] = f0;
        *(float4*)&R[4] = f1;
        *(float4*)&R[8] = f2;
    }
    #pragma unroll
    for (int it = 0; it < 8; ++it) {
        int f = tid + it * 256;
        int row = f >> 6, kc = f & 63;
        float4 L = *(const float4*)&local[((size_t)(base + row)) * 256 + kc * 4];
        uint2 w8; w8.x = pk2bf(L.x, L.y); w8.y = pk2bf(L.z, L.w);
        *(uint2*)&LB[row * 264 + kc * 4] = w8;
    }
    __syncthreads();

    v4f acc[4][2];
    #pragma unroll
    for (int a = 0; a < 4; ++a)
        #pragma unroll
        for (int b = 0; b < 2; ++b) { acc[a][b][0]=0.f; acc[a][b][1]=0.f; acc[a][b][2]=0.f; acc[a][b][3]=0.f; }
    #pragma unroll
    for (int ks = 0; ks < 8; ++ks) {
        v8s bF[2];
        #pragma unroll
        for (int bt = 0; bt < 2; ++bt)
            bF[bt] = *(const v8s*)&LB[(bt*16 + c15) * 264 + ks*32 + hi*8];
        #pragma unroll
        for (int act = 0; act < 4; ++act) {
            v8s aF = *(const v8s*)&W_locT[(size_t)(wid*64 + act*16 + c15) * 256 + ks*32 + hi*8];
            #pragma unroll
            for (int bt = 0; bt < 2; ++bt)
                acc[act][bt] = __builtin_amdgcn_mfma_f32_16x16x32_bf16(aF, bF[bt], acc[act][bt], 0, 0, 0);
        }
    }
    #pragma unroll
    for (int act = 0; act < 4; ++act) {
        const int oc0 = wid*64 + act*16 + hi*4;
        #pragma unroll
        for (int bt = 0; bt < 2; ++bt) {
            const int lrow = bt*16 + c15;
            float4 v;
            v.x = acc[act][bt][0]; v.y = acc[act][bt][1];
            v.z = acc[act][bt][2]; v.w = acc[act][bt][3];
            if (oc0 < 128)
                *(float4*)&loci_ws[(size_t)(base + lrow) * 128 + oc0] = v;
            else
                *(float4*)&locj_ws[(size_t)(base + lrow) * 128 + (oc0 - 128)] = v;
        }
    }
}

// helper: unpack padded R (12 floats) via 3 float4 loads
__device__ __forceinline__ void loadR(const float* __restrict__ R_ws, int n, float* Ri) {
    float4 f0 = *(const float4*)&R_ws[(size_t)n * 12 + 0];
    float4 f1 = *(const float4*)&R_ws[(size_t)n * 12 + 4];
    float4 f2 = *(const float4*)&R_ws[(size_t)n * 12 + 8];
    Ri[0] = f0.x; Ri[1] = f0.y; Ri[2] = f0.z;
    Ri[3] = f0.w; Ri[4] = f1.x; Ri[5] = f1.y;
    Ri[6] = f1.z; Ri[7] = f1.w; Ri[8] = f2.x;
}

// ---------------- pair kernel: 4096 blocks x 512 thr (8 waves), 64 rows; 34.8KB LDS ----------------
__global__ __launch_bounds__(512, 4) void pair_kernel(
    const float* __restrict__ pos, const int* __restrict__ neighbours,
    const int* __restrict__ resi, const int* __restrict__ chain,
    const int* __restrict__ batch, const int* __restrict__ mask,
    const float* __restrict__ b1p, const float* __restrict__ b2,
    const float* __restrict__ R_ws, const float* __restrict__ loci_ws,
    const float* __restrict__ locj_ws,
    const ushort_t* __restrict__ Wcomb, const ushort_t* __restrict__ W1Ts,
    const ushort_t* __restrict__ W2T, float* __restrict__ out)
{
    __shared__ __align__(16) ushort_t SH0[64 * RSTR];   // featB -> pairB; softmax-red alias
    __shared__ __align__(16) ushort_t HT[64 * RSTR];    // LN-red alias; hidden halves
    float2* redLN = (float2*)HT;    // [64][9] — used before HT's first write
    float*  redSM = (float*)SH0;    // [64][5] — used after SH0's last read

    const int tid = threadIdx.x;
    const int ib = blockIdx.x;
    const int base = ib * 2;
    const int wid = tid >> 6, lane = tid & 63, c15 = lane & 15, hi = lane >> 4;

    // ---- neighbor indices for the 4 epilogue rows ----
    int nbv[4], jv[4];
    #pragma unroll
    for (int bt = 0; bt < 4; ++bt) {
        const int rr = bt * 16 + c15;
        nbv[bt] = neighbours[(size_t)(base + (bt >> 1)) * KNBR + (rr & 31)];
        jv[bt] = nbv[bt] < 0 ? 0 : nbv[bt];
    }

    // ---- features: 8 wave-uniform roles, lane = row (0..63) ----
    {
        const int row = lane;
        const int node = base + (row >> 5);
        const int nb_f = neighbours[(size_t)node * KNBR + (row & 31)];
        const int jf = nb_f < 0 ? 0 : nb_f;
        const float cax = pos[(size_t)node*15 + 3], cay = pos[(size_t)node*15 + 4], caz = pos[(size_t)node*15 + 5];
        const float* pj = pos + (size_t)jf * 15;
        const float dx = pj[3] - cax, dy = pj[4] - cay, dz = pj[5] - caz;
        ushort_t* fr = &SH0[row * RSTR];
        float Ri[9];

        #define DOTR(b,X,Y,Z) (Ri[(b)*3]*(X) + Ri[(b)*3+1]*(Y) + Ri[(b)*3+2]*(Z))
        if (wid == 0) {
            const float d = sqrtf(dx*dx + dy*dy + dz*dz);
            v8s v0;
            #pragma unroll
            for (int r = 0; r < 8; ++r) { float a0 = d - (22.f/15.f)*r; v0[r] = (short)f2bf(__expf(-a0*a0*(1.f/3.78125f))); }
            *(v8s*)&fr[0] = v0;
        } else if (wid == 1) {
            const float d = sqrtf(dx*dx + dy*dy + dz*dz);
            v8s v1;
            #pragma unroll
            for (int r = 0; r < 8; ++r) { float a1 = d - (22.f/15.f)*(r + 8); v1[r] = (short)f2bf(__expf(-a1*a1*(1.f/3.78125f))); }
            *(v8s*)&fr[8] = v1;
        } else if (wid == 2) {
            // cols 16..23: dir(3), rot00..rot11
            loadR(R_ws, node, Ri);
            float Rj[9];
            loadR(R_ws, jf, Rj);
            const float d = sqrtf(dx*dx + dy*dy + dz*dz);
            const float inv = 1.f / (d + 1e-8f);
            const float ux = dx*inv, uy = dy*inv, uz = dz*inv;
            #define ROT(b,c) (Ri[(b)*3]*Rj[(c)*3] + Ri[(b)*3+1]*Rj[(c)*3+1] + Ri[(b)*3+2]*Rj[(c)*3+2])
            v8s v0;
            v0[0] = (short)f2bf(DOTR(0, ux, uy, uz));
            v0[1] = (short)f2bf(DOTR(1, ux, uy, uz));
            v0[2] = (short)f2bf(DOTR(2, ux, uy, uz));
            v0[3] = (short)f2bf(ROT(0,0));
            v0[4] = (short)f2bf(ROT(0,1));
            v0[5] = (short)f2bf(ROT(0,2));
            v0[6] = (short)f2bf(ROT(1,0));
            v0[7] = (short)f2bf(ROT(1,1));
            *(v8s*)&fr[16] = v0;
            #undef ROT
        } else if (wid == 3) {
            // cols 24..31: rot12..rot22, pv m0(3), pv m1b0
            loadR(R_ws, node, Ri);
            float Rj[9];
            loadR(R_ws, jf, Rj);
            #define ROT(b,c) (Ri[(b)*3]*Rj[(c)*3] + Ri[(b)*3+1]*Rj[(c)*3+1] + Ri[(b)*3+2]*Rj[(c)*3+2])
            const float p0x = pj[0]-cax, p0y = pj[1]-cay, p0z = pj[2]-caz;
            v8s v1;
            v1[0] = (short)f2bf(ROT(1,2));
            v1[1] = (short)f2bf(ROT(2,0));
            v1[2] = (short)f2bf(ROT(2,1));
            v1[3] = (short)f2bf(ROT(2,2));
            v1[4] = (short)f2bf(DOTR(0, p0x, p0y, p0z));
            v1[5] = (short)f2bf(DOTR(1, p0x, p0y, p0z));
            v1[6] = (short)f2bf(DOTR(2, p0x, p0y, p0z));
            v1[7] = (short)f2bf(DOTR(0, dx, dy, dz));
            *(v8s*)&fr[24] = v1;
            #undef ROT
        } else if (wid == 4) {
            // cols 32..39: m1b1, m1b2, m2*, m3*
            loadR(R_ws, node, Ri);
            const float p2x = pj[6]-cax, p2y = pj[7]-cay, p2z = pj[8]-caz;
            const float p3x = pj[9]-cax, p3y = pj[10]-cay, p3z = pj[11]-caz;
            v8s v;
            v[0] = (short)f2bf(DOTR(1, dx, dy, dz));
            v[1] = (short)f2bf(DOTR(2, dx, dy, dz));
            v[2] = (short)f2bf(DOTR(0, p2x, p2y, p2z));
            v[3] = (short)f2bf(DOTR(1, p2x, p2y, p2z));
            v[4] = (short)f2bf(DOTR(2, p2x, p2y, p2z));
            v[5] = (short)f2bf(DOTR(0, p3x, p3y, p3z));
            v[6] = (short)f2bf(DOTR(1, p3x, p3y, p3z));
            v[7] = (short)f2bf(DOTR(2, p3x, p3y, p3z));
            *(v8s*)&fr[32] = v;
        } else if (wid == 5) {
            // cols 40..47: pv m4(3) + one-hot cols 43..47 (codes 0..4)
            loadR(R_ws, node, Ri);
            const float p4x = pj[12]-cax, p4y = pj[13]-cay, p4z = pj[14]-caz;
            int rel = resi[jf] - resi[node];
            rel = rel < -REL_CLIP ? -REL_CLIP : (rel > REL_CLIP ? REL_CLIP : rel);
            rel += REL_CLIP;
            const int code = ((chain[jf] == chain[node]) && (batch[jf] == batch[node])) ? rel : (REL_DIM - 1);
            v8s v;
            v[0] = (short)f2bf(DOTR(0, p4x, p4y, p4z));
            v[1] = (short)f2bf(DOTR(1, p4x, p4y, p4z));
            v[2] = (short)f2bf(DOTR(2, p4x, p4y, p4z));
            #pragma unroll
            for (int t = 3; t < 8; ++t) v[t] = (short)((code == t - 3) ? 0x3F80 : 0);
            *(v8s*)&fr[40] = v;
        } else if (wid == 6) {
            // chunks 14,15 (cols 112..127): zeros
            const v8s z = {0,0,0,0,0,0,0,0};
            *(v8s*)&fr[112] = z;
            *(v8s*)&fr[120] = z;
        } else {
            // chunks 6..13 (cols 48..111): zeros, then one-hot (codes 5..65 -> cols 48..108); same-wave ordered
            const v8s z = {0,0,0,0,0,0,0,0};
            #pragma unroll
            for (int c = 6; c < 14; ++c) *(v8s*)&fr[c * 8] = z;
            int rel = resi[jf] - resi[node];
            rel = rel < -REL_CLIP ? -REL_CLIP : (rel > REL_CLIP ? REL_CLIP : rel);
            rel += REL_CLIP;
            const int code = ((chain[jf] == chain[node]) && (batch[jf] == batch[node])) ? rel : (REL_DIM - 1);
            if (code >= 5) fr[43 + code] = (ushort_t)0x3F80;
        }
        #undef DOTR
    }
    __syncthreads();   // bar1: featB ready

    // ---- P1: pair GEMM, 8-way wave-split channels (wid*16..+15); LN (folded) in-reg ----
    float mu0, mu1, mu2, mu3, rs0, rs1, rs2, rs3;
    {
        v4f pacc[4];
        #pragma unroll
        for (int bt = 0; bt < 4; ++bt) { pacc[bt][0]=0.f; pacc[bt][1]=0.f; pacc[bt][2]=0.f; pacc[bt][3]=0.f; }
        #pragma unroll
        for (int ks = 0; ks < 4; ++ks) {
            v8s aF = *(const v8s*)&Wcomb[(size_t)(wid*16 + c15) * 128 + ks*32 + hi*8];
            #pragma unroll
            for (int bt = 0; bt < 4; ++bt) {
                v8s bF = *(const v8s*)&SH0[(bt*16 + c15) * RSTR + (ks*4 + hi) * 8];
                pacc[bt] = __builtin_amdgcn_mfma_f32_16x16x32_bf16(aF, bF, pacc[bt], 0, 0, 0);
            }
        }
        const int mi0 = mask[base], mi1 = mask[base + 1];
        const int ch0 = wid*16 + hi*4;
        const float4 li0 = *(const float4*)&loci_ws[(size_t)base * 128 + ch0];
        const float4 li1 = *(const float4*)&loci_ws[(size_t)(base + 1) * 128 + ch0];
        float sA[4], qA[4];
        #pragma unroll
        for (int bt = 0; bt < 4; ++bt) {
            const int min_ = (bt < 2) ? mi0 : mi1;
            const float pm = (min_ != 0 && mask[jv[bt]] != 0 && nbv[bt] != -1) ? 1.f : 0.f;
            const float4 li = (bt < 2) ? li0 : li1;
            const float4 lj = *(const float4*)&locj_ws[(size_t)jv[bt] * 128 + ch0];
            float v0 = (pacc[bt][0] + li.x + lj.x) * pm;
            float v1 = (pacc[bt][1] + li.y + lj.y) * pm;
            float v2 = (pacc[bt][2] + li.z + lj.z) * pm;
            float v3 = (pacc[bt][3] + li.w + lj.w) * pm;
            pacc[bt][0] = v0; pacc[bt][1] = v1; pacc[bt][2] = v2; pacc[bt][3] = v3;
            float s = v0 + v1 + v2 + v3;
            float q = v0*v0 + v1*v1 + v2*v2 + v3*v3;
            s += __shfl_xor(s, 16, 64);  q += __shfl_xor(q, 16, 64);
            s += __shfl_xor(s, 32, 64);  q += __shfl_xor(q, 32, 64);
            sA[bt] = s; qA[bt] = q;
        }
        {
            float ssel = hi == 0 ? sA[0] : hi == 1 ? sA[1] : hi == 2 ? sA[2] : sA[3];
            float qsel = hi == 0 ? qA[0] : hi == 1 ? qA[1] : hi == 2 ? qA[2] : qA[3];
            redLN[lane * 9 + wid] = make_float2(ssel, qsel);
        }
        __syncthreads();   // bar2: redLN ready (HT not yet written)
        #pragma unroll
        for (int bt = 0; bt < 4; ++bt) {
            const int rr = bt*16 + c15;
            float s = 0.f, q = 0.f;
            #pragma unroll
            for (int w = 0; w < 8; ++w) {
                float2 r = redLN[rr*9 + w];
                s += r.x; q += r.y;
            }
            float mu = s * (1.f/128.f);
            float rs = rsqrtf(q * (1.f/128.f) - mu*mu + 1e-5f);
            if (bt == 0) { mu0 = mu; rs0 = rs; }
            else if (bt == 1) { mu1 = mu; rs1 = rs; }
            else if (bt == 2) { mu2 = mu; rs2 = rs; }
            else { mu3 = mu; rs3 = rs; }
        }
        // normalize (z only; gamma/beta folded) -> pairB (chunks wid*2, wid*2+1)
        {
            const int chA = wid*2 + (hi >> 1);
            #pragma unroll
            for (int bt = 0; bt < 4; ++bt) {
                const float mu = bt == 0 ? mu0 : bt == 1 ? mu1 : bt == 2 ? mu2 : mu3;
                const float rs = bt == 0 ? rs0 : bt == 1 ? rs1 : bt == 2 ? rs2 : rs3;
                const float nm = -mu * rs;
                float z0 = fmaf(pacc[bt][0], rs, nm);
                float z1 = fmaf(pacc[bt][1], rs, nm);
                float z2 = fmaf(pacc[bt][2], rs, nm);
                float z3 = fmaf(pacc[bt][3], rs, nm);
                uint2 w8; w8.x = pk2bf(z0, z1); w8.y = pk2bf(z2, z3);
                const int row = bt*16 + c15;
                *(uint2*)&SH0[row * RSTR + chA * 8 + (hi & 1) * 4] = w8;
            }
        }
    }
    __syncthreads();   // bar3: pairB ready (redLN reads done)

    // ---- P4 halves (all 8 waves) + P5 partial accumulate (waves 0-3) ----
    v4f acc5[4];
    #pragma unroll
    for (int bt = 0; bt < 4; ++bt) { acc5[bt][0]=0.f; acc5[bt][1]=0.f; acc5[bt][2]=0.f; acc5[bt][3]=0.f; }
    #pragma unroll
    for (int half = 0; half < 2; ++half) {
        v4f acc4[4];
        #pragma unroll
        for (int bt = 0; bt < 4; ++bt) { acc4[bt][0]=0.f; acc4[bt][1]=0.f; acc4[bt][2]=0.f; acc4[bt][3]=0.f; }
        #pragma unroll
        for (int ks = 0; ks < 4; ++ks) {
            v8s aF = *(const v8s*)&W1Ts[(size_t)(half*128 + wid*16 + c15) * 128 + ks*32 + hi*8];
            #pragma unroll
            for (int bt = 0; bt < 4; ++bt) {
                v8s bF = *(const v8s*)&SH0[(bt*16 + c15) * RSTR + (ks*4 + hi) * 8];
                acc4[bt] = __builtin_amdgcn_mfma_f32_16x16x32_bf16(aF, bF, acc4[bt], 0, 0, 0);
            }
        }
        {
            const int h0 = half*128 + wid*16 + hi*4;
            const float4 bv = *(const float4*)&b1p[h0];
            const int chA = wid*2 + (hi >> 1);
            #pragma unroll
            for (int bt = 0; bt < 4; ++bt) {
                float g0 = gelu_sig(acc4[bt][0] + bv.x);
                float g1 = gelu_sig(acc4[bt][1] + bv.y);
                float g2 = gelu_sig(acc4[bt][2] + bv.z);
                float g3 = gelu_sig(acc4[bt][3] + bv.w);
                uint2 w8; w8.x = pk2bf(g0, g1); w8.y = pk2bf(g2, g3);
                const int row = bt*16 + c15;
                *(uint2*)&HT[row * RSTR + chA * 8 + (hi & 1) * 4] = w8;
            }
        }
        __syncthreads();   // bar4/6: HT half ready
        if (wid < 4) {
            #pragma unroll
            for (int ks = 0; ks < 4; ++ks) {
                v8s aF = *(const v8s*)&W2T[(size_t)(wid*16 + c15) * 256 + half*128 + ks*32 + hi*8];
                #pragma unroll
                for (int bt = 0; bt < 4; ++bt) {
                    v8s bF = *(const v8s*)&HT[(bt*16 + c15) * RSTR + (ks*4 + hi) * 8];
                    acc5[bt] = __builtin_amdgcn_mfma_f32_16x16x32_bf16(aF, bF, acc5[bt], 0, 0, 0);
                }
            }
        }
        if (half == 0) __syncthreads();   // bar5: HT reads done before overwrite
    }

    // ---- softmax (waves 0-3; no max-sub, logits tiny) ----
    {
        if (wid < 4) {
            const float4 bv = *(const float4*)&b2[wid*16 + hi*4];
            float sW[4];
            #pragma unroll
            for (int bt = 0; bt < 4; ++bt) {
                acc5[bt][0] += bv.x; acc5[bt][1] += bv.y; acc5[bt][2] += bv.z; acc5[bt][3] += bv.w;
                float s = __expf(acc5[bt][0]) + __expf(acc5[bt][1])
                        + __expf(acc5[bt][2]) + __expf(acc5[bt][3]);
                s += __shfl_xor(s, 16, 64);
                s += __shfl_xor(s, 32, 64);
                sW[bt] = s;
            }
            float ssel = hi == 0 ? sW[0] : hi == 1 ? sW[1] : hi == 2 ? sW[2] : sW[3];
            redSM[lane * 5 + wid] = ssel;
        }
        __syncthreads();   // bar7: redSM ready
        if (wid < 4) {
            #pragma unroll
            for (int bt = 0; bt < 4; ++bt) {
                const int rr = bt*16 + c15;
                float S = redSM[rr*5+0] + redSM[rr*5+1] + redSM[rr*5+2] + redSM[rr*5+3];
                const float lz = __logf(S);
                float4 o;
                o.x = acc5[bt][0] - lz; o.y = acc5[bt][1] - lz;
                o.z = acc5[bt][2] - lz; o.w = acc5[bt][3] - lz;
                *(float4*)&out[((size_t)(ib * 64 + rr)) * 64 + wid*16 + hi*4] = o;
            }
        }
    }
}

extern "C" void kernel_launch(void* const* d_in, const int* in_sizes, int n_in,
                              void* d_out, int out_size, void* d_ws, size_t ws_size,
                              hipStream_t stream) {
    (void)in_sizes; (void)n_in; (void)out_size; (void)ws_size;
    const float* local   = (const float*)d_in[0];
    const float* pos     = (const float*)d_in[1];
    const int* neighbours= (const int*)d_in[2];
    const int* resi      = (const int*)d_in[3];
    const int* chain     = (const int*)d_in[4];
    const int* batch     = (const int*)d_in[5];
    const int* mask      = (const int*)d_in[6];
    const float* W_relpos= (const float*)d_in[7];
    const float* W_dist  = (const float*)d_in[8];
    const float* W_dir   = (const float*)d_in[9];
    const float* W_rot   = (const float*)d_in[10];
    const float* W_pvec  = (const float*)d_in[11];
    const float* W_loc_i = (const float*)d_in[12];
    const float* W_loc_j = (const float*)d_in[13];
    const float* ln_scale= (const float*)d_in[14];
    const float* ln_bias = (const float*)d_in[15];
    const float* W1      = (const float*)d_in[16];
    const float* b1      = (const float*)d_in[17];
    const float* W2      = (const float*)d_in[18];
    const float* b2      = (const float*)d_in[19];
    float* out = (float*)d_out;

    float* R_ws    = (float*)d_ws;                          // 8192*12 f32 (padded)
    float* loci_ws = R_ws + (size_t)N_NODES * 12;           // 8192*128 f32
    float* locj_ws = loci_ws + (size_t)N_NODES * PDIM;      // 8192*128 f32
    ushort_t* Wcomb = (ushort_t*)(locj_ws + (size_t)N_NODES * PDIM); // 128*128
    ushort_t* W1Ts  = Wcomb + 16384;                        // 256*128
    ushort_t* W2T   = W1Ts + 32768;                         // 64*256
    ushort_t* W_locT= W2T + 16384;                          // 256*256
    float* b1p      = (float*)(W_locT + 65536);             // 256 f32

    hipLaunchKernelGGL(prep_kernel, dim3(514), dim3(256), 0, stream,
                       W_dist, W_dir, W_rot, W_pvec, W_relpos, W1, W2,
                       W_loc_i, W_loc_j, ln_scale, ln_bias, b1,
                       Wcomb, W1Ts, W2T, W_locT, b1p);
    hipLaunchKernelGGL(locframe_kernel, dim3(N_NODES / 32), dim3(256), 0, stream,
                       local, pos, W_locT, R_ws, loci_ws, locj_ws);
    hipLaunchKernelGGL(pair_kernel, dim3(N_NODES / 2), dim3(512), 0, stream,
                       pos, neighbours, resi, chain, batch, mask, b1p, b2,
                       R_ws, loci_ws, locj_ws, Wcomb, W1Ts, W2T, out);
}

// Round 13
// 136.146 us; speedup vs baseline: 1.1439x; 1.1439x over previous
//
#include <hip/hip_runtime.h>
#include <hip/hip_bf16.h>
#include <math.h>

#define N_NODES 8192
#define KNBR    32
#define PDIM    128
#define BINS    64
#define REL_CLIP 32
#define REL_DIM  66
#define RSTR    136   // LDS row stride in ushorts (272B): 4-bank row step, conflict-free, linear chunks

typedef unsigned short ushort_t;
typedef short v8s  __attribute__((ext_vector_type(8)));
typedef float v4f  __attribute__((ext_vector_type(4)));

__device__ __forceinline__ ushort_t f2bf(float f) {
    union { __hip_bfloat16 b; ushort_t u; } cv;
    cv.b = __float2bfloat16(f);
    return cv.u;
}
__device__ __forceinline__ unsigned int pk2bf(float lo, float hiv) {
    union { __hip_bfloat162 h2; unsigned int u; } cv;
    cv.h2 = __float22bfloat162_rn(make_float2(lo, hiv));
    return cv.u;
}
// gelu ~= x * sigmoid(1.702 x); exp(-1.702x) = exp2(-2.4554045x)
__device__ __forceinline__ float gelu_sig(float x) {
    float e = exp2f(-2.4554045f * x);
    return x / (1.f + e);
}

// ---------------- prep: bf16 weights; LN folded into W1/b1 ----------------
__global__ __launch_bounds__(256) void prep_kernel(
    const float* __restrict__ W_dist, const float* __restrict__ W_dir,
    const float* __restrict__ W_rot, const float* __restrict__ W_pvec,
    const float* __restrict__ W_relpos,
    const float* __restrict__ W1, const float* __restrict__ W2,
    const float* __restrict__ W_loc_i, const float* __restrict__ W_loc_j,
    const float* __restrict__ ln_scale, const float* __restrict__ ln_bias,
    const float* __restrict__ b1,
    ushort_t* __restrict__ Wcomb, ushort_t* __restrict__ W1Ts,
    ushort_t* __restrict__ W2T, ushort_t* __restrict__ W_locT,
    float* __restrict__ b1p)
{
    int idx = blockIdx.x * 256 + threadIdx.x;
    if (idx < 16384) {
        int col = idx >> 7, k = idx & 127;
        float v = 0.f;
        if (k < 16)       v = W_dist[k * PDIM + col];
        else if (k < 19)  v = W_dir[(k - 16) * PDIM + col];
        else if (k < 28)  v = W_rot[(k - 19) * PDIM + col];
        else if (k < 43)  v = W_pvec[(k - 28) * PDIM + col];
        else if (k < 109) v = W_relpos[(size_t)(k - 43) * PDIM + col];
        Wcomb[idx] = f2bf(v);
    } else if (idx < 49152) {
        int o = idx - 16384;
        int col = o >> 7, k = o & 127;
        W1Ts[o] = f2bf(W1[(size_t)k * 256 + col] * ln_scale[k]);
    } else if (idx < 65536) {
        int o = idx - 49152;
        int col = o >> 8, k = o & 255;
        W2T[o] = f2bf(W2[(size_t)k * BINS + col]);
    } else if (idx < 131072) {
        int o = idx - 65536;
        int oc = o >> 8, k = o & 255;
        float v = (oc < 128) ? W_loc_i[(size_t)k * 128 + oc]
                             : W_loc_j[(size_t)k * 128 + (oc - 128)];
        W_locT[o] = f2bf(v);
    } else if (idx < 131328) {
        int c = idx - 131072;
        float s = b1[c];
        for (int k = 0; k < 128; ++k) s += ln_bias[k] * W1[(size_t)k * 256 + c];
        b1p[c] = s;
    }
}

// ---------------- locframe: frames + MFMA local projections ----------------
__global__ __launch_bounds__(256) void locframe_kernel(
    const float* __restrict__ local, const float* __restrict__ pos,
    const ushort_t* __restrict__ W_locT,
    float* __restrict__ R_ws, float* __restrict__ loci_ws, float* __restrict__ locj_ws)
{
    __shared__ __align__(16) ushort_t LB[32 * 264];
    const int tid = threadIdx.x;
    const int base = blockIdx.x * 32;
    const int wid = tid >> 6, lane = tid & 63, c15 = lane & 15, hi = lane >> 4;

    if (tid < 32) {  // frames
        const int n = base + tid;
        const float* pp = pos + (size_t)n * 15;
        float nx = pp[0], ny = pp[1], nz = pp[2];
        float cax = pp[3], cay = pp[4], caz = pp[5];
        float cx = pp[6], cy = pp[7], cz = pp[8];
        float e1x = cx - cax, e1y = cy - cay, e1z = cz - caz;
        float n1 = sqrtf(e1x*e1x + e1y*e1y + e1z*e1z) + 1e-8f;
        e1x /= n1; e1y /= n1; e1z /= n1;
        float v2x = nx - cax, v2y = ny - cay, v2z = nz - caz;
        float dp = v2x*e1x + v2y*e1y + v2z*e1z;
        float wx = v2x - dp*e1x, wy = v2y - dp*e1y, wz = v2z - dp*e1z;
        float n2 = sqrtf(wx*wx + wy*wy + wz*wz) + 1e-8f;
        float e2x = wx/n2, e2y = wy/n2, e2z = wz/n2;
        float4 f0, f1, f2;
        f0.x = e1x; f0.y = e1y; f0.z = e1z; f0.w = e2x;
        f1.x = e2y; f1.y = e2z;
        f1.z = e1y*e2z - e1z*e2y;
        f1.w = e1z*e2x - e1x*e2z;
        f2.x = e1x*e2y - e1y*e2x;
        f2.y = 0.f; f2.z = 0.f; f2.w = 0.f;
        float* R = R_ws + (size_t)n * 12;
        *(float4*)&R[0] = f0;
        *(float4*)&R[4] = f1;
        *(float4*)&R[8] = f2;
    }
    #pragma unroll
    for (int it = 0; it < 8; ++it) {
        int f = tid + it * 256;
        int row = f >> 6, kc = f & 63;
        float4 L = *(const float4*)&local[((size_t)(base + row)) * 256 + kc * 4];
        uint2 w8; w8.x = pk2bf(L.x, L.y); w8.y = pk2bf(L.z, L.w);
        *(uint2*)&LB[row * 264 + kc * 4] = w8;
    }
    __syncthreads();

    v4f acc[4][2];
    #pragma unroll
    for (int a = 0; a < 4; ++a)
        #pragma unroll
        for (int b = 0; b < 2; ++b) { acc[a][b][0]=0.f; acc[a][b][1]=0.f; acc[a][b][2]=0.f; acc[a][b][3]=0.f; }
    #pragma unroll
    for (int ks = 0; ks < 8; ++ks) {
        v8s bF[2];
        #pragma unroll
        for (int bt = 0; bt < 2; ++bt)
            bF[bt] = *(const v8s*)&LB[(bt*16 + c15) * 264 + ks*32 + hi*8];
        #pragma unroll
        for (int act = 0; act < 4; ++act) {
            v8s aF = *(const v8s*)&W_locT[(size_t)(wid*64 + act*16 + c15) * 256 + ks*32 + hi*8];
            #pragma unroll
            for (int bt = 0; bt < 2; ++bt)
                acc[act][bt] = __builtin_amdgcn_mfma_f32_16x16x32_bf16(aF, bF[bt], acc[act][bt], 0, 0, 0);
        }
    }
    #pragma unroll
    for (int act = 0; act < 4; ++act) {
        const int oc0 = wid*64 + act*16 + hi*4;
        #pragma unroll
        for (int bt = 0; bt < 2; ++bt) {
            const int lrow = bt*16 + c15;
            float4 v;
            v.x = acc[act][bt][0]; v.y = acc[act][bt][1];
            v.z = acc[act][bt][2]; v.w = acc[act][bt][3];
            if (oc0 < 128)
                *(float4*)&loci_ws[(size_t)(base + lrow) * 128 + oc0] = v;
            else
                *(float4*)&locj_ws[(size_t)(base + lrow) * 128 + (oc0 - 128)] = v;
        }
    }
}

// helper: unpack padded R (12 floats) via 3 float4 loads
__device__ __forceinline__ void loadR(const float* __restrict__ R_ws, int n, float* Ri) {
    float4 f0 = *(const float4*)&R_ws[(size_t)n * 12 + 0];
    float4 f1 = *(const float4*)&R_ws[(size_t)n * 12 + 4];
    float4 f2 = *(const float4*)&R_ws[(size_t)n * 12 + 8];
    Ri[0] = f0.x; Ri[1] = f0.y; Ri[2] = f0.z;
    Ri[3] = f0.w; Ri[4] = f1.x; Ri[5] = f1.y;
    Ri[6] = f1.z; Ri[7] = f1.w; Ri[8] = f2.x;
}

// ---------------- pair kernel: 4096 blocks x 256 thr, 64 rows; 34.8KB LDS ----------------
// wave-uniform feature roles (wid-split); linear chunk addressing on 272B-stride LDS
__global__ __launch_bounds__(256, 3) void pair_kernel(
    const float* __restrict__ pos, const int* __restrict__ neighbours,
    const int* __restrict__ resi, const int* __restrict__ chain,
    const int* __restrict__ batch, const int* __restrict__ mask,
    const float* __restrict__ b1p, const float* __restrict__ b2,
    const float* __restrict__ R_ws, const float* __restrict__ loci_ws,
    const float* __restrict__ locj_ws,
    const ushort_t* __restrict__ Wcomb, const ushort_t* __restrict__ W1Ts,
    const ushort_t* __restrict__ W2T, float* __restrict__ out)
{
    __shared__ __align__(16) ushort_t SH0[64 * RSTR];   // featB -> pairB; softmax-red alias
    __shared__ __align__(16) ushort_t HT[64 * RSTR];    // LN-red alias; hidden halves
    float2* redLN = (float2*)HT;    // [64][5] — used before HT's first write
    float*  redSM = (float*)SH0;    // [64][5] — used after SH0's last read

    const int tid = threadIdx.x;
    const int ib = blockIdx.x;
    const int base = ib * 2;
    const int wid = tid >> 6, lane = tid & 63, c15 = lane & 15, hi = lane >> 4;

    // ---- neighbor indices for the 4 epilogue rows ----
    int nbv[4], jv[4];
    #pragma unroll
    for (int bt = 0; bt < 4; ++bt) {
        const int rr = bt * 16 + c15;
        nbv[bt] = neighbours[(size_t)(base + (bt >> 1)) * KNBR + (rr & 31)];
        jv[bt] = nbv[bt] < 0 ? 0 : nbv[bt];
    }

    // ---- features: wave-uniform roles, lane = row (0..63) ----
    {
        const int row = lane;
        const int node = base + (row >> 5);
        const int nb_f = neighbours[(size_t)node * KNBR + (row & 31)];
        const int jf = nb_f < 0 ? 0 : nb_f;
        const float cax = pos[(size_t)node*15 + 3], cay = pos[(size_t)node*15 + 4], caz = pos[(size_t)node*15 + 5];
        const float* pj = pos + (size_t)jf * 15;
        const float dx = pj[3] - cax, dy = pj[4] - cay, dz = pj[5] - caz;
        ushort_t* fr = &SH0[row * RSTR];
        float Ri[9];

        #define DOTR(b,X,Y,Z) (Ri[(b)*3]*(X) + Ri[(b)*3+1]*(Y) + Ri[(b)*3+2]*(Z))
        if (wid == 0) {
            // cols 0..15: RBF
            const float d = sqrtf(dx*dx + dy*dy + dz*dz);
            v8s v0, v1;
            #pragma unroll
            for (int r = 0; r < 8; ++r) {
                float a0 = d - (22.f/15.f)*r;        v0[r] = (short)f2bf(__expf(-a0*a0*(1.f/3.78125f)));
                float a1 = d - (22.f/15.f)*(r + 8);  v1[r] = (short)f2bf(__expf(-a1*a1*(1.f/3.78125f)));
            }
            *(v8s*)&fr[0] = v0;
            *(v8s*)&fr[8] = v1;
        } else if (wid == 1) {
            // cols 16..31: dir(3), rot(9), pv m0(3), pv m1b0
            loadR(R_ws, node, Ri);
            float Rj[9];
            loadR(R_ws, jf, Rj);
            const float d = sqrtf(dx*dx + dy*dy + dz*dz);
            const float inv = 1.f / (d + 1e-8f);
            const float ux = dx*inv, uy = dy*inv, uz = dz*inv;
            #define ROT(b,c) (Ri[(b)*3]*Rj[(c)*3] + Ri[(b)*3+1]*Rj[(c)*3+1] + Ri[(b)*3+2]*Rj[(c)*3+2])
            const float p0x = pj[0]-cax, p0y = pj[1]-cay, p0z = pj[2]-caz;
            v8s v0, v1;
            v0[0] = (short)f2bf(DOTR(0, ux, uy, uz));
            v0[1] = (short)f2bf(DOTR(1, ux, uy, uz));
            v0[2] = (short)f2bf(DOTR(2, ux, uy, uz));
            v0[3] = (short)f2bf(ROT(0,0));
            v0[4] = (short)f2bf(ROT(0,1));
            v0[5] = (short)f2bf(ROT(0,2));
            v0[6] = (short)f2bf(ROT(1,0));
            v0[7] = (short)f2bf(ROT(1,1));
            v1[0] = (short)f2bf(ROT(1,2));
            v1[1] = (short)f2bf(ROT(2,0));
            v1[2] = (short)f2bf(ROT(2,1));
            v1[3] = (short)f2bf(ROT(2,2));
            v1[4] = (short)f2bf(DOTR(0, p0x, p0y, p0z));
            v1[5] = (short)f2bf(DOTR(1, p0x, p0y, p0z));
            v1[6] = (short)f2bf(DOTR(2, p0x, p0y, p0z));
            v1[7] = (short)f2bf(DOTR(0, dx, dy, dz));
            *(v8s*)&fr[16] = v0;
            *(v8s*)&fr[24] = v1;
            #undef ROT
        } else if (wid == 2) {
            // cols 32..39: pv (m1b1, m1b2, m2*, m3*)
            loadR(R_ws, node, Ri);
            const float p2x = pj[6]-cax, p2y = pj[7]-cay, p2z = pj[8]-caz;
            const float p3x = pj[9]-cax, p3y = pj[10]-cay, p3z = pj[11]-caz;
            v8s v;
            v[0] = (short)f2bf(DOTR(1, dx, dy, dz));
            v[1] = (short)f2bf(DOTR(2, dx, dy, dz));
            v[2] = (short)f2bf(DOTR(0, p2x, p2y, p2z));
            v[3] = (short)f2bf(DOTR(1, p2x, p2y, p2z));
            v[4] = (short)f2bf(DOTR(2, p2x, p2y, p2z));
            v[5] = (short)f2bf(DOTR(0, p3x, p3y, p3z));
            v[6] = (short)f2bf(DOTR(1, p3x, p3y, p3z));
            v[7] = (short)f2bf(DOTR(2, p3x, p3y, p3z));
            *(v8s*)&fr[32] = v;
        } else {
            // cols 40..127: pv m4 (3), zeros, one-hot via single u16 store (same-wave ordered)
            loadR(R_ws, node, Ri);
            const float p4x = pj[12]-cax, p4y = pj[13]-cay, p4z = pj[14]-caz;
            v8s v = {0,0,0,0,0,0,0,0};
            v[0] = (short)f2bf(DOTR(0, p4x, p4y, p4z));
            v[1] = (short)f2bf(DOTR(1, p4x, p4y, p4z));
            v[2] = (short)f2bf(DOTR(2, p4x, p4y, p4z));
            *(v8s*)&fr[40] = v;
            const v8s z = {0,0,0,0,0,0,0,0};
            #pragma unroll
            for (int c = 6; c < 16; ++c) *(v8s*)&fr[c * 8] = z;
            int rel = resi[jf] - resi[node];
            rel = rel < -REL_CLIP ? -REL_CLIP : (rel > REL_CLIP ? REL_CLIP : rel);
            rel += REL_CLIP;
            const int code = ((chain[jf] == chain[node]) && (batch[jf] == batch[node])) ? rel : (REL_DIM - 1);
            fr[43 + code] = (ushort_t)0x3F80;   // after zero fill; same wave -> ordered
        }
        #undef DOTR
    }
    __syncthreads();   // bar1: featB ready

    // ---- P1: pair GEMM, wave-split channels; LN (folded) in-reg ----
    float mu0, mu1, mu2, mu3, rs0, rs1, rs2, rs3;
    {
        v4f pacc[2][4];
        #pragma unroll
        for (int at = 0; at < 2; ++at)
            #pragma unroll
            for (int bt = 0; bt < 4; ++bt) { pacc[at][bt][0]=0.f; pacc[at][bt][1]=0.f; pacc[at][bt][2]=0.f; pacc[at][bt][3]=0.f; }
        #pragma unroll
        for (int ks = 0; ks < 4; ++ks) {
            v8s bF[4];
            #pragma unroll
            for (int bt = 0; bt < 4; ++bt)
                bF[bt] = *(const v8s*)&SH0[(bt*16 + c15) * RSTR + (ks*4 + hi) * 8];
            #pragma unroll
            for (int at = 0; at < 2; ++at) {
                v8s aF = *(const v8s*)&Wcomb[(size_t)((wid*2 + at)*16 + c15) * 128 + ks*32 + hi*8];
                #pragma unroll
                for (int bt = 0; bt < 4; ++bt)
                    pacc[at][bt] = __builtin_amdgcn_mfma_f32_16x16x32_bf16(aF, bF[bt], pacc[at][bt], 0, 0, 0);
            }
        }
        const int mi0 = mask[base], mi1 = mask[base + 1];
        float pmv[4];
        #pragma unroll
        for (int bt = 0; bt < 4; ++bt) {
            const int min_ = (bt < 2) ? mi0 : mi1;
            pmv[bt] = (min_ != 0 && mask[jv[bt]] != 0 && nbv[bt] != -1) ? 1.f : 0.f;
        }
        float4 liA[2][2], ljA[2][4];
        #pragma unroll
        for (int at = 0; at < 2; ++at) {
            const int ch0 = wid*32 + at*16 + hi*4;
            liA[at][0] = *(const float4*)&loci_ws[(size_t)base * 128 + ch0];
            liA[at][1] = *(const float4*)&loci_ws[(size_t)(base + 1) * 128 + ch0];
            #pragma unroll
            for (int bt = 0; bt < 4; ++bt)
                ljA[at][bt] = *(const float4*)&locj_ws[(size_t)jv[bt] * 128 + ch0];
        }
        float sA[4], qA[4];
        #pragma unroll
        for (int bt = 0; bt < 4; ++bt) {
            float s = 0.f, q = 0.f;
            #pragma unroll
            for (int at = 0; at < 2; ++at) {
                const float4 li = (bt < 2) ? liA[at][0] : liA[at][1];
                const float4 lj = ljA[at][bt];
                float v0 = (pacc[at][bt][0] + li.x + lj.x) * pmv[bt];
                float v1 = (pacc[at][bt][1] + li.y + lj.y) * pmv[bt];
                float v2 = (pacc[at][bt][2] + li.z + lj.z) * pmv[bt];
                float v3 = (pacc[at][bt][3] + li.w + lj.w) * pmv[bt];
                pacc[at][bt][0] = v0; pacc[at][bt][1] = v1; pacc[at][bt][2] = v2; pacc[at][bt][3] = v3;
                s += v0 + v1 + v2 + v3;
                q += v0*v0 + v1*v1 + v2*v2 + v3*v3;
            }
            s += __shfl_xor(s, 16, 64);  q += __shfl_xor(q, 16, 64);
            s += __shfl_xor(s, 32, 64);  q += __shfl_xor(q, 32, 64);
            sA[bt] = s; qA[bt] = q;
        }
        {
            float ssel = hi == 0 ? sA[0] : hi == 1 ? sA[1] : hi == 2 ? sA[2] : sA[3];
            float qsel = hi == 0 ? qA[0] : hi == 1 ? qA[1] : hi == 2 ? qA[2] : qA[3];
            redLN[lane * 5 + wid] = make_float2(ssel, qsel);
        }
        __syncthreads();   // bar2: redLN ready (HT not yet written)
        #pragma unroll
        for (int bt = 0; bt < 4; ++bt) {
            const int rr = bt*16 + c15;
            float2 r0 = redLN[rr*5+0], r1 = redLN[rr*5+1], r2 = redLN[rr*5+2], r3 = redLN[rr*5+3];
            float s = r0.x + r1.x + r2.x + r3.x;
            float q = r0.y + r1.y + r2.y + r3.y;
            float mu = s * (1.f/128.f);
            float rs = rsqrtf(q * (1.f/128.f) - mu*mu + 1e-5f);
            if (bt == 0) { mu0 = mu; rs0 = rs; }
            else if (bt == 1) { mu1 = mu; rs1 = rs; }
            else if (bt == 2) { mu2 = mu; rs2 = rs; }
            else { mu3 = mu; rs3 = rs; }
        }
        // normalize (z only; gamma/beta folded) -> pairB
        #pragma unroll
        for (int at = 0; at < 2; ++at) {
            const int chA = wid*4 + at*2 + (hi >> 1);
            #pragma unroll
            for (int bt = 0; bt < 4; ++bt) {
                const float mu = bt == 0 ? mu0 : bt == 1 ? mu1 : bt == 2 ? mu2 : mu3;
                const float rs = bt == 0 ? rs0 : bt == 1 ? rs1 : bt == 2 ? rs2 : rs3;
                const float nm = -mu * rs;
                float z0 = fmaf(pacc[at][bt][0], rs, nm);
                float z1 = fmaf(pacc[at][bt][1], rs, nm);
                float z2 = fmaf(pacc[at][bt][2], rs, nm);
                float z3 = fmaf(pacc[at][bt][3], rs, nm);
                uint2 w8; w8.x = pk2bf(z0, z1); w8.y = pk2bf(z2, z3);
                const int row = bt*16 + c15;
                *(uint2*)&SH0[row * RSTR + chA * 8 + (hi & 1) * 4] = w8;
            }
        }
    }
    __syncthreads();   // bar3: pairB ready (redLN reads done)

    // ---- P4 halves + P5 partial accumulate ----
    v4f acc5[4];
    #pragma unroll
    for (int bt = 0; bt < 4; ++bt) { acc5[bt][0]=0.f; acc5[bt][1]=0.f; acc5[bt][2]=0.f; acc5[bt][3]=0.f; }
    #pragma unroll
    for (int half = 0; half < 2; ++half) {
        v4f acc4[2][4];
        #pragma unroll
        for (int at = 0; at < 2; ++at)
            #pragma unroll
            for (int bt = 0; bt < 4; ++bt) { acc4[at][bt][0]=0.f; acc4[at][bt][1]=0.f; acc4[at][bt][2]=0.f; acc4[at][bt][3]=0.f; }
        #pragma unroll
        for (int ks = 0; ks < 4; ++ks) {
            v8s bF[4];
            #pragma unroll
            for (int bt = 0; bt < 4; ++bt)
                bF[bt] = *(const v8s*)&SH0[(bt*16 + c15) * RSTR + (ks*4 + hi) * 8];
            #pragma unroll
            for (int at = 0; at < 2; ++at) {
                v8s aF = *(const v8s*)&W1Ts[(size_t)(half*128 + wid*32 + at*16 + c15) * 128 + ks*32 + hi*8];
                #pragma unroll
                for (int bt = 0; bt < 4; ++bt)
                    acc4[at][bt] = __builtin_amdgcn_mfma_f32_16x16x32_bf16(aF, bF[bt], acc4[at][bt], 0, 0, 0);
            }
        }
        #pragma unroll
        for (int at = 0; at < 2; ++at) {
            const int h0 = half*128 + wid*32 + at*16 + hi*4;
            const float4 bv = *(const float4*)&b1p[h0];
            const int chA = wid*4 + at*2 + (hi >> 1);
            #pragma unroll
            for (int bt = 0; bt < 4; ++bt) {
                float g0 = gelu_sig(acc4[at][bt][0] + bv.x);
                float g1 = gelu_sig(acc4[at][bt][1] + bv.y);
                float g2 = gelu_sig(acc4[at][bt][2] + bv.z);
                float g3 = gelu_sig(acc4[at][bt][3] + bv.w);
                uint2 w8; w8.x = pk2bf(g0, g1); w8.y = pk2bf(g2, g3);
                const int row = bt*16 + c15;
                *(uint2*)&HT[row * RSTR + chA * 8 + (hi & 1) * 4] = w8;
            }
        }
        __syncthreads();   // bar4/6: HT half ready
        #pragma unroll
        for (int ks = 0; ks < 4; ++ks) {
            v8s aF = *(const v8s*)&W2T[(size_t)(wid*16 + c15) * 256 + half*128 + ks*32 + hi*8];
            #pragma unroll
            for (int bt = 0; bt < 4; ++bt) {
                v8s bF = *(const v8s*)&HT[(bt*16 + c15) * RSTR + (ks*4 + hi) * 8];
                acc5[bt] = __builtin_amdgcn_mfma_f32_16x16x32_bf16(aF, bF, acc5[bt], 0, 0, 0);
            }
        }
        if (half == 0) __syncthreads();   // bar5: HT reads done before overwrite
    }

    // ---- softmax (no max-sub; logits tiny): per-wave partial sums ----
    {
        const float4 bv = *(const float4*)&b2[wid*16 + hi*4];
        float sW[4];
        #pragma unroll
        for (int bt = 0; bt < 4; ++bt) {
            acc5[bt][0] += bv.x; acc5[bt][1] += bv.y; acc5[bt][2] += bv.z; acc5[bt][3] += bv.w;
            float s = __expf(acc5[bt][0]) + __expf(acc5[bt][1])
                    + __expf(acc5[bt][2]) + __expf(acc5[bt][3]);
            s += __shfl_xor(s, 16, 64);
            s += __shfl_xor(s, 32, 64);
            sW[bt] = s;
        }
        {
            float ssel = hi == 0 ? sW[0] : hi == 1 ? sW[1] : hi == 2 ? sW[2] : sW[3];
            redSM[lane * 5 + wid] = ssel;
        }
        __syncthreads();   // bar7: redSM ready
        #pragma unroll
        for (int bt = 0; bt < 4; ++bt) {
            const int rr = bt*16 + c15;
            float S = redSM[rr*5+0] + redSM[rr*5+1] + redSM[rr*5+2] + redSM[rr*5+3];
            const float lz = __logf(S);
            float4 o;
            o.x = acc5[bt][0] - lz; o.y = acc5[bt][1] - lz;
            o.z = acc5[bt][2] - lz; o.w = acc5[bt][3] - lz;
            *(float4*)&out[((size_t)(ib * 64 + rr)) * 64 + wid*16 + hi*4] = o;
        }
    }
}

extern "C" void kernel_launch(void* const* d_in, const int* in_sizes, int n_in,
                              void* d_out, int out_size, void* d_ws, size_t ws_size,
                              hipStream_t stream) {
    (void)in_sizes; (void)n_in; (void)out_size; (void)ws_size;
    const float* local   = (const float*)d_in[0];
    const float* pos     = (const float*)d_in[1];
    const int* neighbours= (const int*)d_in[2];
    const int* resi      = (const int*)d_in[3];
    const int* chain     = (const int*)d_in[4];
    const int* batch     = (const int*)d_in[5];
    const int* mask      = (const int*)d_in[6];
    const float* W_relpos= (const float*)d_in[7];
    const float* W_dist  = (const float*)d_in[8];
    const float* W_dir   = (const float*)d_in[9];
    const float* W_rot   = (const float*)d_in[10];
    const float* W_pvec  = (const float*)d_in[11];
    const float* W_loc_i = (const float*)d_in[12];
    const float* W_loc_j = (const float*)d_in[13];
    const float* ln_scale= (const float*)d_in[14];
    const float* ln_bias = (const float*)d_in[15];
    const float* W1      = (const float*)d_in[16];
    const float* b1      = (const float*)d_in[17];
    const float* W2      = (const float*)d_in[18];
    const float* b2      = (const float*)d_in[19];
    float* out = (float*)d_out;

    float* R_ws    = (float*)d_ws;                          // 8192*12 f32 (padded)
    float* loci_ws = R_ws + (size_t)N_NODES * 12;           // 8192*128 f32
    float* locj_ws = loci_ws + (size_t)N_NODES * PDIM;      // 8192*128 f32
    ushort_t* Wcomb = (ushort_t*)(locj_ws + (size_t)N_NODES * PDIM); // 128*128
    ushort_t* W1Ts  = Wcomb + 16384;                        // 256*128
    ushort_t* W2T   = W1Ts + 32768;                         // 64*256
    ushort_t* W_locT= W2T + 16384;                          // 256*256
    float* b1p      = (float*)(W_locT + 65536);             // 256 f32

    hipLaunchKernelGGL(prep_kernel, dim3(514), dim3(256), 0, stream,
                       W_dist, W_dir, W_rot, W_pvec, W_relpos, W1, W2,
                       W_loc_i, W_loc_j, ln_scale, ln_bias, b1,
                       Wcomb, W1Ts, W2T, W_locT, b1p);
    hipLaunchKernelGGL(locframe_kernel, dim3(N_NODES / 32), dim3(256), 0, stream,
                       local, pos, W_locT, R_ws, loci_ws, locj_ws);
    hipLaunchKernelGGL(pair_kernel, dim3(N_NODES / 2), dim3(256), 0, stream,
                       pos, neighbours, resi, chain, batch, mask, b1p, b2,
                       R_ws, loci_ws, locj_ws, Wcomb, W1Ts, W2T, out);
}